// Round 9
// baseline (10037.323 us; speedup 1.0000x reference)
//
#include <hip/hip_runtime.h>

// Problem constants
#define Bn   512
#define Tn   1024
#define Fn   64
#define Hn   512
#define NGRP 16                  // groups: 32 batch rows each
#define GMEM 9                   // members per group: 8 L1 + 1 L2
#define NBLK (NGRP * GMEM)       // 144 blocks
#define TRIES (1L << 22)
#define SLD  516                 // padded LDS slice stride (shorts): bank-shift 2/row
#define TLD  68                  // padded LDS tile stride (shorts)

typedef short bf16x8 __attribute__((ext_vector_type(8)));
typedef float f32x4  __attribute__((ext_vector_type(4)));

__device__ __forceinline__ short f2bf(float f) {
    union { float f; unsigned u; } v; v.f = f;
    unsigned r = (v.u + 0x7FFFu + ((v.u >> 16) & 1u)) >> 16;  // RNE
    return (short)(unsigned short)r;
}
__device__ __forceinline__ float sigm(float x) { return 1.f / (1.f + __expf(-x)); }
__device__ __forceinline__ float tanh_(float x) { return 2.f / (1.f + __expf(-2.f * x)) - 1.f; }

__device__ __forceinline__ bf16x8 cvt8(const float* p) {
    const float4 v0 = *(const float4*)p;
    const float4 v1 = *(const float4*)(p + 4);
    bf16x8 a;
    a[0] = f2bf(v0.x); a[1] = f2bf(v0.y); a[2] = f2bf(v0.z); a[3] = f2bf(v0.w);
    a[4] = f2bf(v1.x); a[5] = f2bf(v1.y); a[6] = f2bf(v1.z); a[7] = f2bf(v1.w);
    return a;
}

// -------- device-coherent exchange primitives (proven R7/R8) --------
__device__ __forceinline__ void ldx16(bf16x8& d, const short* p) {
    asm volatile("global_load_dwordx4 %0, %1, off sc0 sc1" : "=v"(d) : "v"(p));
}
__device__ __forceinline__ void stx16(short* p, bf16x8 v) {
    asm volatile("global_store_dwordx4 %0, %1, off sc0 sc1" :: "v"(p), "v"(v) : "memory");
}
#define VMWAIT(N) do { \
    asm volatile("s_waitcnt vmcnt(" #N ")" ::: "memory"); \
    __builtin_amdgcn_sched_barrier(0); } while (0)

__device__ __forceinline__ int aldi(const int* p) {
    return __hip_atomic_load(p, __ATOMIC_RELAXED, __HIP_MEMORY_SCOPE_AGENT);
}

// ---- per-member flag barrier (R3/R7/R8 protocol) ----
// flag[m] = k  <=>  member m finished step k-1 AND the stores it drained before
// publishing are visible. NOTE (R9): L1 drains ONLY h before the flag; its c
// stores drain during the NEXT step's staging vmcnt(0), so c1(t) is guaranteed
// visible once the producer's flag reaches t+2.
__device__ __forceinline__ void flag_arrive(int* slot, int val) {
    asm volatile("s_waitcnt vmcnt(0)" ::: "memory");
    __builtin_amdgcn_sched_barrier(0);
    __syncthreads();
    if (threadIdx.x == 0)
        __hip_atomic_store(slot, val, __ATOMIC_RELEASE, __HIP_MEMORY_SCOPE_AGENT);
}
// lanes 0..7 wait for the 8 L1 flags >= tgtA; lane 8 waits for the L2 flag >= tgtB
__device__ __forceinline__ void flag_wait(const int* flags, int tgtA, int tgtB) {
    const int lane = threadIdx.x & 63;
    const int tgt = (lane < 8) ? tgtA : tgtB;
    long spins = 0;
    for (;;) {
        bool ok = (lane >= GMEM) || (aldi(flags + lane) >= tgt);
        if (__all(ok)) break;
        if (++spins > TRIES) break;   // safety valve
        __builtin_amdgcn_s_sleep(1);
    }
    __atomic_signal_fence(__ATOMIC_ACQUIRE);
    __builtin_amdgcn_sched_barrier(0);
}

// ---------------- prepack (unchanged layouts) ----------------
// w1f: [ut 32][kb 18][gate 4][n 16][kk 32]  (gcol = gate*512 + ut*16 + n, k = kb*32+kk)
// w2f: [ut4 4][kb 18][gate 4][n 16][kk 32]  (gcol = gate*64 + ut4*16 + n)
__global__ void prep_kernel(const float* __restrict__ Wih1, const float* __restrict__ Whh1,
                            const float* __restrict__ Wih2, const float* __restrict__ Whh2,
                            const float* __restrict__ bih1, const float* __restrict__ bhh1,
                            const float* __restrict__ bih2, const float* __restrict__ bhh2,
                            short* __restrict__ h1g, short* __restrict__ c1g,
                            short* __restrict__ w1f, short* __restrict__ w2f,
                            float* __restrict__ bs1, float* __restrict__ bs2,
                            int* __restrict__ bar) {
    const int i0 = blockIdx.x * blockDim.x + threadIdx.x;
    const int stride = gridDim.x * blockDim.x;
    for (int i = i0; i < 1024; i += stride) bar[i] = 0;                // 16 groups x 32 ints
    for (int i = i0; i < 2 * Bn * Hn; i += stride) h1g[i] = 0;
    for (int i = i0; i < 3 * Bn * Hn; i += stride) c1g[i] = 0;
    for (int i = i0; i < 2048 * 576; i += stride) {
        int kk = i & 31, n = (i >> 5) & 15, ct = (i >> 9) & 3;
        int r = i >> 11; int kb = r % 18; int ut = r / 18;
        int gcol = ct * 512 + ut * 16 + n;
        int k = kb * 32 + kk;
        float v = (k < 64) ? Wih1[gcol * 64 + k] : Whh1[gcol * 512 + (k - 64)];
        w1f[i] = f2bf(v);
    }
    for (int i = i0; i < 256 * 576; i += stride) {
        int kk = i & 31, n = (i >> 5) & 15, ct = (i >> 9) & 3;
        int r = i >> 11; int kb = r % 18; int ut4 = r / 18;
        int gcol = ct * 64 + ut4 * 16 + n;
        int k = kb * 32 + kk;
        float v = (k < 512) ? Wih2[gcol * 512 + k] : Whh2[gcol * 64 + (k - 512)];
        w2f[i] = f2bf(v);
    }
    for (int i = i0; i < 2048; i += stride) bs1[i] = bih1[i] + bhh1[i];
    for (int i = i0; i < 256;  i += stride) bs2[i] = bih2[i] + bhh2[i];
}

// ---------------- main persistent kernel ----------------
// 144 blocks x 256 threads (wvc = wave = 16-unit column tile). 16 groups x 32
// batch rows: 8 L1 blocks (64 units each) + 1 L2 block per group.
// R9 changes vs R8:
//  (a) c stores issued AFTER the flag (drain off the L1->L1 critical path);
//      c1 is TRIPLE-buffered (parity t%3); L2 waits L1 flags >= t+2.
//  (b) own 64 h-dims read from the block's LDS tile (pre-wait, into registers)
//      -> stage only the 7 peer chunks (28KB).
//  (c) padded LDS strides (SLD=516, TLD=68) -> A-reads ~conflict-free.
// LDS (shorts): [0, 32*SLD) staged slice; tile0/tile1 = 32*TLD each after it.
// Flag targets (flag k <=> finished step k-1):
//   L1@t: L1 flags >= t (RAW h1(t-1) + WAR h1), L2 flag >= t-2 (WAR c1 parity t%3)
//   L2@t: L1 flags >= t+2 (RAW c1(t), incl. its deferred drain), own >= t (trivial)
// L1 publishes a FINAL flag Tn+1 after draining its last c stores.
__global__ __launch_bounds__(256, 1) void lstm_kernel(
    const float* __restrict__ data,
    const short* __restrict__ w1f, const float* __restrict__ bs1,
    const short* __restrict__ w2f, const float* __restrict__ bs2,
    short* __restrict__ h1g, short* __restrict__ c1g,
    float* __restrict__ out, int* __restrict__ bar) {
    extern __shared__ short smem[];
    const int tid = threadIdx.x;
    const int lane = tid & 63, wv = tid >> 6;
    const int n = lane & 15, q = lane >> 4;
    const int wvc = wv;
    const int bid = blockIdx.x;
    const int rt = bid / GMEM, role = bid % GMEM;
    const f32x4 Z4 = {0.f, 0.f, 0.f, 0.f};
    const int rowbase = rt * 32;
    int* grp = bar + rt * 32;
    short* tile0 = smem + 32 * SLD;          // h tile (L1) / h2 parity 0 (L2)
    short* tile1 = tile0 + 32 * TLD;         // c tile (L1) / h2 parity 1 (L2)
    const int r0 = rowbase + n, r1 = rowbase + 16 + n;
    const int lr0 = n, lr1 = n + 16, sw = n & 7;
    const int srow = tid >> 3, sd8 = tid & 7;      // staging decomposition

    if (role < 8) {
        // ---------------- LSTM1 ----------------
        const int ut = role * 4 + wvc;
        const int ucol = ut * 16 + n;
        const float bi_ = bs1[ucol], bf_ = bs1[512 + ucol], bg_ = bs1[1024 + ucol], bo_ = bs1[1536 + ucol];
        const short* wbase = w1f + ut * 36864 + n * 32 + q * 8;

        // recurrent weights (kb 2..17) -> registers, once
        bf16x8 wr[16][4];
#pragma unroll
        for (int kb = 0; kb < 16; ++kb)
#pragma unroll
            for (int g = 0; g < 4; ++g)
                wr[kb][g] = *(const bf16x8*)(wbase + ((kb + 2) * 4 + g) * 512);

        // zero tile0 (h(-1) = 0 for the pre-wait own-chunk reads at t=0)
        for (int i = tid; i < 32 * TLD; i += 256) tile0[i] = 0;
        __syncthreads();

        f32x4 c1f[2]; c1f[0] = Z4; c1f[1] = Z4;

        for (int t = 0; t < Tn; ++t) {
            const short* h1r = h1g + (t & 1) * (Bn * Hn);
            short* h1w = h1g + ((t + 1) & 1) * (Bn * Hn);
            short* c1w = c1g + (t % 3) * (Bn * Hn);
            f32x4 acc[2][4];
#pragma unroll
            for (int a = 0; a < 2; ++a)
#pragma unroll
                for (int g = 0; g < 4; ++g) acc[a][g] = Z4;

            // x part (kb 0,1): cached loads, before the wait (hides under spin)
            const float* x0 = data + (size_t)r0 * 65536 + t * 64;
            const float* x1 = data + (size_t)r1 * 65536 + t * 64;
#pragma unroll
            for (int kb = 0; kb < 2; ++kb) {
                const bf16x8 a0 = cvt8(x0 + kb * 32 + q * 8);
                const bf16x8 a1 = cvt8(x1 + kb * 32 + q * 8);
#pragma unroll
                for (int g = 0; g < 4; ++g) {
                    const bf16x8 b = *(const bf16x8*)(wbase + (kb * 4 + g) * 512);
                    acc[0][g] = __builtin_amdgcn_mfma_f32_16x16x32_bf16(a0, b, acc[0][g], 0, 0, 0);
                    acc[1][g] = __builtin_amdgcn_mfma_f32_16x16x32_bf16(a1, b, acc[1][g], 0, 0, 0);
                }
            }
            // own 64 h-dims: h(t-1) still in tile0 from step t-1 -> registers.
            // (compile-time indexed; tile0 is not rewritten until this step's
            //  epilogue, which is after the staging __syncthreads.)
            bf16x8 aOwn[2][2];
#pragma unroll
            for (int kl = 0; kl < 2; ++kl) {
                aOwn[kl][0] = *(const bf16x8*)&tile0[lr0 * TLD + ((((kl * 4 + q)) ^ sw) * 8)];
                aOwn[kl][1] = *(const bf16x8*)&tile0[lr1 * TLD + ((((kl * 4 + q)) ^ sw) * 8)];
            }

            flag_wait(grp, t, t - 2);   // peers' h1(t-1); L2 done with c1 parity t%3

            // ---- stage the 7 PEER chunks (28KB) into the padded slice ----
            // outstanding at entry: <=1 deferred c store from t-1 (in-order
            // retire: vmcnt(3) after 7 loads => loads 0..3 complete).
            const short* gsrc = h1r + (size_t)rowbase * 512;
            bf16x8 st[7];
            __builtin_amdgcn_sched_barrier(0);
#pragma unroll
            for (int i = 0; i < 7; ++i) {
                const int p = (role + 1 + i) & 7;
                ldx16(st[i], gsrc + srow * 512 + p * 64 + sd8 * 8);
            }
            VMWAIT(3);
#pragma unroll
            for (int i = 0; i < 4; ++i) {
                const int p = (role + 1 + i) & 7;
                *(bf16x8*)&smem[srow * SLD + ((p * 8 + (sd8 ^ (srow & 7))) * 8)] = st[i];
            }
            VMWAIT(0);
#pragma unroll
            for (int i = 4; i < 7; ++i) {
                const int p = (role + 1 + i) & 7;
                *(bf16x8*)&smem[srow * SLD + ((p * 8 + (sd8 ^ (srow & 7))) * 8)] = st[i];
            }
            __syncthreads();

            // ---- h part: peers from the slice, own kb from registers ----
#pragma unroll
            for (int kb = 0; kb < 16; ++kb) {
                bf16x8 a0, a1;
                if ((kb >> 1) == role) {
                    a0 = aOwn[kb & 1][0];
                    a1 = aOwn[kb & 1][1];
                } else {
                    a0 = *(const bf16x8*)&smem[lr0 * SLD + (((kb * 4 + q) ^ sw) * 8)];
                    a1 = *(const bf16x8*)&smem[lr1 * SLD + (((kb * 4 + q) ^ sw) * 8)];
                }
#pragma unroll
                for (int g = 0; g < 4; ++g) {
                    acc[0][g] = __builtin_amdgcn_mfma_f32_16x16x32_bf16(a0, wr[kb][g], acc[0][g], 0, 0, 0);
                    acc[1][g] = __builtin_amdgcn_mfma_f32_16x16x32_bf16(a1, wr[kb][g], acc[1][g], 0, 0, 0);
                }
            }

            // ---- epilogue: gates -> LDS tiles (swizzled transpose) ----
#pragma unroll
            for (int rt16 = 0; rt16 < 2; ++rt16) {
#pragma unroll
                for (int r = 0; r < 4; ++r) {
                    const float xi = acc[rt16][0][r] + bi_;
                    const float xf = acc[rt16][1][r] + bf_;
                    const float xg = acc[rt16][2][r] + bg_;
                    const float xo = acc[rt16][3][r] + bo_;
                    const float ii = sigm(xi), ff = sigm(xf), gg = tanh_(xg), oo = sigm(xo);
                    const float c = ff * c1f[rt16][r] + ii * gg;
                    c1f[rt16][r] = c;
                    const float h = oo * tanh_(c);
                    const int lr = rt16 * 16 + q * 4 + r;      // 0..31
                    const int lu = wvc * 16 + n;               // 0..63
                    const int slot = ((lu >> 3) ^ (lr & 7)) * 8 + (lu & 7);
                    tile0[lr * TLD + slot] = f2bf(h);
                    tile1[lr * TLD + slot] = f2bf(c);
                }
            }
            __syncthreads();
            // h store -> flag (drains h only) -> deferred c store
            {
                const int row = tid >> 3, part = tid & 7;
                const int slot = (part ^ (row & 7)) * 8;
                const bf16x8 hv = *(const bf16x8*)&tile0[row * TLD + slot];
                const bf16x8 cv = *(const bf16x8*)&tile1[row * TLD + slot];
                short* gdst = h1w + (size_t)(rowbase + row) * 512 + role * 64 + part * 8;
                short* gdc  = c1w + (size_t)(rowbase + row) * 512 + role * 64 + part * 8;
                stx16(gdst, hv);
                flag_arrive(grp + role, t + 1);   // vmcnt(0): h drained; barrier; flag
                stx16(gdc, cv);                   // drains during next staging / final
            }
        }
        flag_arrive(grp + role, Tn + 1);          // drain last c stores, final flag
    } else {
        // ---------------- LSTM2 (one per group; h2 internal in LDS tiles) ----------------
        const int ut4 = wvc;
        const int ucol = ut4 * 16 + n;
        const float bi_ = bs2[ucol], bf_ = bs2[64 + ucol], bg_ = bs2[128 + ucol], bo_ = bs2[192 + ucol];
        const short* wbase = w2f + ut4 * 36864 + n * 32 + q * 8;

        // c1-part weights (kb 0..15) + h2 tail weights (kb 16,17) -> registers
        bf16x8 wr[16][4];
#pragma unroll
        for (int kb = 0; kb < 16; ++kb)
#pragma unroll
            for (int g = 0; g < 4; ++g)
                wr[kb][g] = *(const bf16x8*)(wbase + (kb * 4 + g) * 512);
        bf16x8 wh[2][4];
#pragma unroll
        for (int kb2 = 0; kb2 < 2; ++kb2)
#pragma unroll
            for (int g = 0; g < 4; ++g)
                wh[kb2][g] = *(const bf16x8*)(wbase + ((16 + kb2) * 4 + g) * 512);

        // zero both h2 parity tiles (h2(-1) = 0)
        for (int i = tid; i < 64 * TLD; i += 256) tile0[i] = 0;
        __syncthreads();

        f32x4 c2f[2]; c2f[0] = Z4; c2f[1] = Z4;

        for (int t = 0; t < Tn; ++t) {
            flag_wait(grp, t + 2, t);        // c1(t) visible (deferred drain) ; own trivial
            const short* c1r = c1g + (t % 3) * (Bn * Hn);
            const short* h2rd = (t & 1) ? tile1 : tile0;
            short* h2wr = (t & 1) ? tile0 : tile1;
            f32x4 acc[2][4];
#pragma unroll
            for (int a = 0; a < 2; ++a)
#pragma unroll
                for (int g = 0; g < 4; ++g) acc[a][g] = Z4;

            // ---- stage the group's 32x512 c1 slice (8 chunks/thread) ----
            const short* gsrc = c1r + (size_t)rowbase * 512;
            bf16x8 st[8];
            __builtin_amdgcn_sched_barrier(0);
#pragma unroll
            for (int i = 0; i < 8; ++i) ldx16(st[i], gsrc + (i * 256 + tid) * 8);
            VMWAIT(4);
#pragma unroll
            for (int i = 0; i < 4; ++i) {
                const int row = i * 4 + wv; const int col = lane;
                *(bf16x8*)&smem[row * SLD + ((col >> 3) * 8 + ((col & 7) ^ (row & 7))) * 8] = st[i];
            }
            VMWAIT(0);
#pragma unroll
            for (int i = 4; i < 8; ++i) {
                const int row = i * 4 + wv; const int col = lane;
                *(bf16x8*)&smem[row * SLD + ((col >> 3) * 8 + ((col & 7) ^ (row & 7))) * 8] = st[i];
            }
            __syncthreads();

            // ---- c1 part (staged slice) ----
#pragma unroll
            for (int kb = 0; kb < 16; ++kb) {
                const bf16x8 a0 = *(const bf16x8*)&smem[lr0 * SLD + (((kb * 4 + q) ^ sw) * 8)];
                const bf16x8 a1 = *(const bf16x8*)&smem[lr1 * SLD + (((kb * 4 + q) ^ sw) * 8)];
#pragma unroll
                for (int g = 0; g < 4; ++g) {
                    acc[0][g] = __builtin_amdgcn_mfma_f32_16x16x32_bf16(a0, wr[kb][g], acc[0][g], 0, 0, 0);
                    acc[1][g] = __builtin_amdgcn_mfma_f32_16x16x32_bf16(a1, wr[kb][g], acc[1][g], 0, 0, 0);
                }
            }
            // ---- h2 part (LDS parity tile, swizzled) ----
#pragma unroll
            for (int kb2 = 0; kb2 < 2; ++kb2) {
                const bf16x8 a0 = *(const bf16x8*)&h2rd[lr0 * TLD + (((kb2 * 4 + q) ^ sw) * 8)];
                const bf16x8 a1 = *(const bf16x8*)&h2rd[lr1 * TLD + (((kb2 * 4 + q) ^ sw) * 8)];
#pragma unroll
                for (int g = 0; g < 4; ++g) {
                    acc[0][g] = __builtin_amdgcn_mfma_f32_16x16x32_bf16(a0, wh[kb2][g], acc[0][g], 0, 0, 0);
                    acc[1][g] = __builtin_amdgcn_mfma_f32_16x16x32_bf16(a1, wh[kb2][g], acc[1][g], 0, 0, 0);
                }
            }

            // ---- epilogue: out (cached f32) + h2 -> next parity tile ----
#pragma unroll
            for (int rt16 = 0; rt16 < 2; ++rt16) {
#pragma unroll
                for (int r = 0; r < 4; ++r) {
                    const float xi = acc[rt16][0][r] + bi_;
                    const float xf = acc[rt16][1][r] + bf_;
                    const float xg = acc[rt16][2][r] + bg_;
                    const float xo = acc[rt16][3][r] + bo_;
                    const float ii = sigm(xi), ff = sigm(xf), gg = tanh_(xg), oo = sigm(xo);
                    const float c = ff * c2f[rt16][r] + ii * gg;
                    c2f[rt16][r] = c;
                    const float h = oo * tanh_(c);
                    const int lr = rt16 * 16 + q * 4 + r;       // 0..31
                    const int lu = wvc * 16 + n;                // 0..63
                    out[(size_t)(rowbase + lr) * 65536 + (size_t)t * 64 + ucol] = c;  // output is c2
                    h2wr[lr * TLD + ((lu >> 3) ^ (lr & 7)) * 8 + (lu & 7)] = f2bf(h);
                }
            }
            flag_arrive(grp + 8, t + 1);   // also the barrier protecting h2 parity reuse
        }
    }
}

extern "C" void kernel_launch(void* const* d_in, const int* in_sizes, int n_in,
                              void* d_out, int out_size, void* d_ws, size_t ws_size,
                              hipStream_t stream) {
    const float* data = (const float*)d_in[0];
    const float* Wih1 = (const float*)d_in[1];
    const float* Whh1 = (const float*)d_in[2];
    const float* bih1 = (const float*)d_in[3];
    const float* bhh1 = (const float*)d_in[4];
    const float* Wih2 = (const float*)d_in[5];
    const float* Whh2 = (const float*)d_in[6];
    const float* bih2 = (const float*)d_in[7];
    const float* bhh2 = (const float*)d_in[8];
    float* out = (float*)d_out;

    char* w = (char*)d_ws;
    short* h1g = (short*)(w + 0);          // 2 * 512*512*2 = 1,048,576
    short* c1g = (short*)(w + 1048576);    // 3 * 512*512*2 = 1,572,864
    short* w2f = (short*)(w + 2621440);    // 256*576*2 = 294,912
    short* w1f = (short*)(w + 2916352);    // 2048*576*2 = 2,359,296
    float* bs1 = (float*)(w + 5275648);    // 8,192
    float* bs2 = (float*)(w + 5283840);    // 1,024
    int* bar  = (int*)(w + 5284864);       // 4 KB: 16 groups x 32 ints

    hipLaunchKernelGGL(prep_kernel, dim3(1024), dim3(256), 0, stream,
                       Wih1, Whh1, Wih2, Whh2, bih1, bhh1, bih2, bhh2,
                       h1g, c1g, w1f, w2f, bs1, bs2, bar);

    // dynamic LDS: slice 32*SLD + 2 tiles 32*TLD, in shorts -> bytes
    const int lds_bytes = (32 * SLD + 64 * TLD) * 2;   // 41,728
    hipLaunchKernelGGL(lstm_kernel, dim3(NBLK), dim3(256), lds_bytes, stream,
                       data, w1f, bs1, w2f, bs2, h1g, c1g, out, bar);
}